// Round 5
// baseline (161.306 us; speedup 1.0000x reference)
//
#include <hip/hip_runtime.h>

#define H 1024
#define SEQ 4096

typedef float f32x4 __attribute__((ext_vector_type(4)));
typedef short s16x8 __attribute__((ext_vector_type(8)));
typedef unsigned short u16;
typedef u16 u16x4 __attribute__((ext_vector_type(4)));
typedef u16 u16x8 __attribute__((ext_vector_type(8)));

__device__ inline u16 f2bf(float f) {
  union { float f; unsigned u; } v; v.f = f;
  unsigned r = v.u + 0x7fffu + ((v.u >> 16) & 1u);
  return (u16)(r >> 16);
}
__device__ inline float bf2f(u16 b) {
  union { unsigned u; float f; } v; v.u = ((unsigned)b) << 16; return v.f;
}

__device__ __forceinline__ void cvt16(const float* __restrict__ src, u16* __restrict__ dst, int i) {
  const float4* s = reinterpret_cast<const float4*>(src) + (size_t)i * 4;
  float4 a = s[0], b = s[1], c = s[2], d = s[3];
  u16x8 lo, hi;
  lo[0]=f2bf(a.x); lo[1]=f2bf(a.y); lo[2]=f2bf(a.z); lo[3]=f2bf(a.w);
  lo[4]=f2bf(b.x); lo[5]=f2bf(b.y); lo[6]=f2bf(b.z); lo[7]=f2bf(b.w);
  hi[0]=f2bf(c.x); hi[1]=f2bf(c.y); hi[2]=f2bf(c.z); hi[3]=f2bf(c.w);
  hi[4]=f2bf(d.x); hi[5]=f2bf(d.y); hi[6]=f2bf(d.z); hi[7]=f2bf(d.w);
  u16x8* o = reinterpret_cast<u16x8*>(dst) + (size_t)i * 2;
  o[0] = lo; o[1] = hi;
}

// =============== prep: Wq transpose, Wk/Wv/x cvt, wgs/zeros ===============
__global__ __launch_bounds__(256) void prep_kernel(
    const float* __restrict__ Wq, const float* __restrict__ Wk,
    const float* __restrict__ Wv, const float* __restrict__ x,
    const float* __restrict__ Wg,
    u16* __restrict__ wqTb, u16* __restrict__ wkb, u16* __restrict__ wvb,
    u16* __restrict__ xb, float* __restrict__ wgs, float* __restrict__ zeros) {
  __shared__ u16 tls[64][65];
  int blk = blockIdx.x, t = threadIdx.x;
  if (blk < 256) {
    int ti = blk >> 4, tj = blk & 15;
    int lr = t >> 2, cq = (t & 3) * 16;
    const float* s = Wq + (size_t)(ti * 64 + lr) * H + tj * 64 + cq;
#pragma unroll
    for (int q = 0; q < 4; ++q) {
      float4 v = *reinterpret_cast<const float4*>(s + q * 4);
      tls[lr][cq + q * 4 + 0] = f2bf(v.x);
      tls[lr][cq + q * 4 + 1] = f2bf(v.y);
      tls[lr][cq + q * 4 + 2] = f2bf(v.z);
      tls[lr][cq + q * 4 + 3] = f2bf(v.w);
    }
    __syncthreads();
    u16x8 a, b2;
#pragma unroll
    for (int i = 0; i < 8; ++i) a[i] = tls[cq + i][lr];
#pragma unroll
    for (int i = 0; i < 8; ++i) b2[i] = tls[cq + 8 + i][lr];
    u16* d = wqTb + (size_t)(tj * 64 + lr) * H + ti * 64 + cq;
    *reinterpret_cast<u16x8*>(d) = a;
    *reinterpret_cast<u16x8*>(d + 8) = b2;
  } else if (blk < 512) {
    cvt16(Wk, wkb, (blk - 256) * 256 + t);
  } else if (blk < 768) {
    cvt16(Wv, wvb, (blk - 512) * 256 + t);
  } else if (blk < 896) {
    cvt16(x, xb, (blk - 768) * 256 + t);
  } else {
    int i = t * 4;
    float4 a = *reinterpret_cast<const float4*>(Wg + i);
    float4 b2 = *reinterpret_cast<const float4*>(Wg + H + i);
    float4 o; o.x=a.x+b2.x; o.y=a.y+b2.y; o.z=a.z+b2.z; o.w=a.w+b2.w;
    *reinterpret_cast<float4*>(wgs + i) = o;
    float4 z; z.x=0.f; z.y=0.f; z.z=0.f; z.w=0.f;
    *reinterpret_cast<float4*>(zeros + i) = z;
  }
}

// ---- shared GEMM body: out = A(bf16 MxK) * W^T(bf16 NxK) + bias ----
__device__ __forceinline__ void gemm_body(const u16* __restrict__ A, const u16* __restrict__ W,
                                          const float* __restrict__ bias, u16* __restrict__ out,
                                          int mt, int nt, int omode, u16* sm) {
  int m0 = mt * 128, n0 = nt * 128;
  int t = threadIdx.x;
  int wave = t >> 6, lane = t & 63;
  int lane15 = lane & 15, lhi = lane >> 4;
  int wr = wave >> 1, wc = wave & 1;
  u16* a_sm = sm;
  u16* b_sm = sm + 8192;

  f32x4 acc[4][4];
#pragma unroll
  for (int mi = 0; mi < 4; ++mi)
#pragma unroll
    for (int ni = 0; ni < 4; ++ni) acc[mi][ni] = (f32x4)0.f;

  int rsel = wave * 32 + (lane >> 3);
  int csel = (lane & 7) * 8;
  const u16* Ab = A + (size_t)m0 * H + csel;
  const u16* Wb = W + (size_t)n0 * H + csel;

  for (int kt = 0; kt < 16; ++kt) {
    int kc = kt * 64;
#pragma unroll
    for (int j = 0; j < 4; ++j) {
      const u16* ga = Ab + (size_t)(rsel + j * 8) * H + kc;
      const u16* gb = Wb + (size_t)(rsel + j * 8) * H + kc;
      __builtin_amdgcn_global_load_lds((const __attribute__((address_space(1))) unsigned int*)ga,
                                       (__attribute__((address_space(3))) unsigned int*)&a_sm[wave * 2048 + j * 512],
                                       16, 0, 0);
      __builtin_amdgcn_global_load_lds((const __attribute__((address_space(1))) unsigned int*)gb,
                                       (__attribute__((address_space(3))) unsigned int*)&b_sm[wave * 2048 + j * 512],
                                       16, 0, 0);
    }
    __syncthreads();
#pragma unroll
    for (int ks = 0; ks < 2; ++ks) {
      s16x8 af[4], bfr[4];
#pragma unroll
      for (int mi = 0; mi < 4; ++mi)
        af[mi] = *reinterpret_cast<const s16x8*>(&a_sm[(wr * 64 + mi * 16 + lane15) * 64 + ks * 32 + lhi * 8]);
#pragma unroll
      for (int ni = 0; ni < 4; ++ni)
        bfr[ni] = *reinterpret_cast<const s16x8*>(&b_sm[(wc * 64 + ni * 16 + lane15) * 64 + ks * 32 + lhi * 8]);
#pragma unroll
      for (int mi = 0; mi < 4; ++mi)
#pragma unroll
        for (int ni = 0; ni < 4; ++ni)
          acc[mi][ni] = __builtin_amdgcn_mfma_f32_16x16x32_bf16(af[mi], bfr[ni], acc[mi][ni], 0, 0, 0);
    }
    __syncthreads();
  }

  float bqv[4];
#pragma unroll
  for (int ni = 0; ni < 4; ++ni) bqv[ni] = bias[n0 + wc * 64 + ni * 16 + lane15];

  if (omode == 0) {
#pragma unroll
    for (int mi = 0; mi < 4; ++mi)
#pragma unroll
      for (int ni = 0; ni < 4; ++ni)
#pragma unroll
        for (int r = 0; r < 4; ++r)
          sm[(wr * 64 + mi * 16 + lhi * 4 + r) * 128 + wc * 64 + ni * 16 + lane15] =
              f2bf(acc[mi][ni][r] + bqv[ni]);
    __syncthreads();
#pragma unroll
    for (int i = 0; i < 4; ++i) {
      int lin2 = i * 4096 + t * 16;
      int row = lin2 >> 7, col = lin2 & 127;
      u16x8 v0 = *reinterpret_cast<const u16x8*>(&sm[lin2]);
      u16x8 v1 = *reinterpret_cast<const u16x8*>(&sm[lin2 + 8]);
      u16* o = out + (size_t)(m0 + row) * H + n0 + col;
      *reinterpret_cast<u16x8*>(o) = v0;
      *reinterpret_cast<u16x8*>(o + 8) = v1;
    }
  } else {
#pragma unroll
    for (int mi = 0; mi < 4; ++mi)
#pragma unroll
      for (int ni = 0; ni < 4; ++ni) {
        int col = n0 + wc * 64 + ni * 16 + lane15;
#pragma unroll
        for (int r = 0; r < 4; ++r) {
          int row = m0 + wr * 64 + mi * 16 + lhi * 4 + r;
          out[((size_t)(row >> 6) * H + col) * 64 + (row & 63)] = f2bf(acc[mi][ni][r] + bqv[ni]);
        }
      }
  }
}

// kv1: k = x.Wk^T + bk (row-major), vT = (x.Wv^T + bv)^T
__global__ __launch_bounds__(256) void kv1_kernel(const u16* __restrict__ xb,
                                                  const u16* __restrict__ wkb, const u16* __restrict__ wvb,
                                                  const float* __restrict__ bk, const float* __restrict__ bv,
                                                  u16* __restrict__ kbf, u16* __restrict__ vTb) {
  __shared__ __align__(16) u16 sm[128 * 128];
  int sel = blockIdx.x >> 5;
  int bid = blockIdx.x & 31;
  if (sel == 0)
    gemm_body(xb, wkb, bk, kbf, bid >> 3, bid & 7, 0, sm);
  else
    gemm_body(xb, wvb, bv, vTb, bid >> 3, bid & 7, 2, sm);
}

// kv2: blocks 0-31: ktilde = k.Wq; blocks 32-39: vg = vT.Wg0, bqk = k.bq
__global__ __launch_bounds__(256) void kv2_kernel(const u16* __restrict__ kbf,
                                                  const u16* __restrict__ wqTb,
                                                  const float* __restrict__ zeros,
                                                  u16* __restrict__ ktb,
                                                  const u16* __restrict__ vTb,
                                                  const float* __restrict__ Wg,
                                                  const float* __restrict__ bq,
                                                  float* __restrict__ vg, float* __restrict__ bqk) {
  if (blockIdx.x < 32) {
    __shared__ __align__(16) u16 sm[128 * 128];
    gemm_body(kbf, wqTb, zeros, ktb, blockIdx.x >> 3, blockIdx.x & 7, 0, sm);
  } else {
    __shared__ float bq_s[H];
    __shared__ float partial[4][64];
    int b = blockIdx.x - 32, t = threadIdx.x;
    *reinterpret_cast<float4*>(&bq_s[t * 4]) = *reinterpret_cast<const float4*>(bq + t * 4);
    int l = t & 63, part = t >> 6;
    float s = 0.f;
    const u16* vtp = vTb + ((size_t)b * H + part * 256) * 64 + l;
    for (int h = 0; h < 256; ++h) s += bf2f(vtp[h * 64]) * Wg[part * 256 + h];
    partial[part][l] = s;
    __syncthreads();
    if (t < 64) vg[b * 64 + t] = partial[0][t] + partial[1][t] + partial[2][t] + partial[3][t];
    int row = t >> 2, qp = t & 3;
    const u16* kr = kbf + ((size_t)b * 64 + row) * H + qp * 256;
    float sb = 0.f;
    for (int j = 0; j < 256; j += 8) {
      u16x8 v8 = *reinterpret_cast<const u16x8*>(kr + j);
      const float* bqp = &bq_s[qp * 256 + j];
#pragma unroll
      for (int i2 = 0; i2 < 8; ++i2) sb += bf2f(v8[i2]) * bqp[i2];
    }
    sb += __shfl_xor(sb, 1);
    sb += __shfl_xor(sb, 2);
    if (qp == 0) bqk[b * 64 + row] = sb;
  }
}

// =============== fused attention: 16-row tiles, p staged ONCE to LDS bf16, floor HBM traffic ===============
// Stage: 16 rows x 4KB read linearly (2KB contiguous per wave instr round), cvt->bf16, XOR-swz LDS.
// Phase 1: wave w owns k-range [w*256,+256): A from LDS, K~ from L2. Sp[4][16x64] partials.
// Softmax: 16 thr/row: reduce partials + bq, exp (no max-sub), row sums + gate dot pg (p from LDS).
// PV: wave owns H-slice [w*256,+256); residual p from LDS (NO second global p read); write out.
// HBM per block: 64 KB read + 64 KB write = floor. 2048 blocks, 3/CU, 2.67 generations.
__global__ __launch_bounds__(256, 3) void attn_kernel(
    const float* __restrict__ p, const u16* __restrict__ ktb,
    const u16* __restrict__ vT, const float* __restrict__ wgs,
    const float* __restrict__ vg, const float* __restrict__ bqk,
    const float* __restrict__ bg, float* __restrict__ out) {
  int t = threadIdx.x;
  int orig = blockIdx.x;
  int lin = (orig & 7) * 256 + (orig >> 3);  // batch-per-XCD locality (2048 = 8*256)
  int b = lin >> 8, st = lin & 255;
  size_t gm0 = (size_t)b * SEQ + (size_t)st * 16;
  int wave = t >> 6, lane = t & 63, lane15 = lane & 15, lhi = lane >> 4;

  __shared__ __align__(16) u16 p_lds[16 * 1024];   // 32 KB bf16 p-tile; 16B slot s of row r at s^(r&7)
  __shared__ __align__(16) float Sp[4][1024];      // 16 KB S-partials; PV scratch aliases
  __shared__ __align__(16) u16 P_lds[16 * 72];     // 2.25 KB
  __shared__ float vg_l[64], bq_l[64], gs_l[16];

  if (t < 64) { vg_l[t] = vg[b * 64 + t]; bq_l[t] = bqk[b * 64 + t]; }

  // ---- stage p-tile (16 x 1024 f32 -> bf16 LDS), contiguous reads ----
  {
    int srow = t >> 7;            // 0..1
    int scol = t & 127;           // 16B slot within row
    const float* gp = p + (gm0 + srow) * H + scol * 8;
    f32x4 r0[8], r1[8];
#pragma unroll
    for (int i = 0; i < 8; ++i) {
      r0[i] = *reinterpret_cast<const f32x4*>(gp + (size_t)(2 * i) * H);
      r1[i] = *reinterpret_cast<const f32x4*>(gp + (size_t)(2 * i) * H + 4);
    }
#pragma unroll
    for (int i = 0; i < 8; ++i) {
      int row = 2 * i + srow;
      u16x8 o;
      o[0]=f2bf(r0[i][0]); o[1]=f2bf(r0[i][1]); o[2]=f2bf(r0[i][2]); o[3]=f2bf(r0[i][3]);
      o[4]=f2bf(r1[i][0]); o[5]=f2bf(r1[i][1]); o[6]=f2bf(r1[i][2]); o[7]=f2bf(r1[i][3]);
      *reinterpret_cast<u16x8*>(&p_lds[row * 1024 + ((scol ^ (row & 7)) << 3)]) = o;
    }
  }
  __syncthreads();

  // ---- phase 1: S-partial over wave's k-range; A from LDS, K~ from L2 ----
  {
    const u16* kb = ktb + ((size_t)b * 64 + lane15) * H + lhi * 8;
    f32x4 acc[4];
#pragma unroll
    for (int ni = 0; ni < 4; ++ni) acc[ni] = (f32x4)0.f;
    int arow = lane15 * 1024;
    int aswz = lane15 & 7;

#pragma unroll 1
    for (int kt = 0; kt < 8; ++kt) {
      int kc = wave * 256 + kt * 32;
      int sb = (kc >> 3) + lhi;
      s16x8 a = *reinterpret_cast<const s16x8*>(&p_lds[arow + ((sb ^ aswz) << 3)]);
      s16x8 k0 = *reinterpret_cast<const s16x8*>(kb + kc);
      s16x8 k1 = *reinterpret_cast<const s16x8*>(kb + (size_t)16 * H + kc);
      s16x8 k2 = *reinterpret_cast<const s16x8*>(kb + (size_t)32 * H + kc);
      s16x8 k3 = *reinterpret_cast<const s16x8*>(kb + (size_t)48 * H + kc);
      acc[0] = __builtin_amdgcn_mfma_f32_16x16x32_bf16(a, k0, acc[0], 0, 0, 0);
      acc[1] = __builtin_amdgcn_mfma_f32_16x16x32_bf16(a, k1, acc[1], 0, 0, 0);
      acc[2] = __builtin_amdgcn_mfma_f32_16x16x32_bf16(a, k2, acc[2], 0, 0, 0);
      acc[3] = __builtin_amdgcn_mfma_f32_16x16x32_bf16(a, k3, acc[3], 0, 0, 0);
    }
    float* sp = &Sp[wave][0];
#pragma unroll
    for (int ni = 0; ni < 4; ++ni)
#pragma unroll
      for (int r = 0; r < 4; ++r)
        sp[(lhi * 4 + r) * 64 + ni * 16 + lane15] = acc[ni][r];
  }
  __syncthreads();

  // ---- softmax + gate: 16 threads per row ----
  {
    int row = t >> 4, q = t & 15;
    int cq = q * 4;
    f32x4 s4 = *reinterpret_cast<const f32x4*>(&Sp[0][row * 64 + cq]);
    s4 += *reinterpret_cast<const f32x4*>(&Sp[1][row * 64 + cq]);
    s4 += *reinterpret_cast<const f32x4*>(&Sp[2][row * 64 + cq]);
    s4 += *reinterpret_cast<const f32x4*>(&Sp[3][row * 64 + cq]);
    float ev[4], se = 0.f, sv = 0.f;
#pragma unroll
    for (int j = 0; j < 4; ++j) {
      float e = __expf(s4[j] + bq_l[cq + j]);
      ev[j] = e; se += e; sv += e * vg_l[cq + j];
    }
    // gate dot pg over H-slice [q*64,+64) from LDS p (bf16)
    float pg = 0.f;
    int prow = row * 1024, pswz = row & 7;
#pragma unroll
    for (int k8 = 0; k8 < 8; ++k8) {
      int s = q * 8 + k8;
      u16x8 pv8 = *reinterpret_cast<const u16x8*>(&p_lds[prow + ((s ^ pswz) << 3)]);
      const float* w_ = wgs + q * 64 + k8 * 8;
      pg += bf2f(pv8[0]) * w_[0] + bf2f(pv8[1]) * w_[1] + bf2f(pv8[2]) * w_[2] + bf2f(pv8[3]) * w_[3]
          + bf2f(pv8[4]) * w_[4] + bf2f(pv8[5]) * w_[5] + bf2f(pv8[6]) * w_[6] + bf2f(pv8[7]) * w_[7];
    }
    se += __shfl_xor(se, 1); se += __shfl_xor(se, 2); se += __shfl_xor(se, 4); se += __shfl_xor(se, 8);
    sv += __shfl_xor(sv, 1); sv += __shfl_xor(sv, 2); sv += __shfl_xor(sv, 4); sv += __shfl_xor(sv, 8);
    pg += __shfl_xor(pg, 1); pg += __shfl_xor(pg, 2); pg += __shfl_xor(pg, 4); pg += __shfl_xor(pg, 8);
    u16x4 pw;
#pragma unroll
    for (int j = 0; j < 4; ++j) pw[j] = f2bf(ev[j]);
    *reinterpret_cast<u16x4*>(&P_lds[row * 72 + cq]) = pw;
    if (q == 0) {
      float inv = 1.f / (32.f * se);
      float logit = sv * inv + pg + bg[0];
      gs_l[row] = inv / (1.f + __expf(-logit));
    }
  }
  __syncthreads();

  // ---- PV + epilogue: out = p + gs*(raw PV); wave owns H-slice [wave*256,+256); residual from LDS ----
  {
    s16x8 pa[2];
#pragma unroll
    for (int ks = 0; ks < 2; ++ks)
      pa[ks] = *reinterpret_cast<const s16x8*>(&P_lds[lane15 * 72 + ks * 32 + lhi * 8]);

    const u16* vb = vT + (size_t)b * H * 64;
    float* sc = &Sp[0][0] + wave * 1024;  // [16][64] per-wave scratch (aliases consumed Sp)
#pragma unroll
    for (int hcc = 0; hcc < 4; ++hcc) {
      int hbase = wave * 256 + hcc * 64;
      f32x4 acc[4];
#pragma unroll
      for (int ni = 0; ni < 4; ++ni) acc[ni] = (f32x4)0.f;
#pragma unroll
      for (int ks = 0; ks < 2; ++ks) {
        s16x8 bv8[4];
#pragma unroll
        for (int ni = 0; ni < 4; ++ni)
          bv8[ni] = *reinterpret_cast<const s16x8*>(vb + (size_t)(hbase + ni * 16 + lane15) * 64 + ks * 32 + lhi * 8);
#pragma unroll
        for (int ni = 0; ni < 4; ++ni)
          acc[ni] = __builtin_amdgcn_mfma_f32_16x16x32_bf16(pa[ks], bv8[ni], acc[ni], 0, 0, 0);
      }
      int swz = (lhi & 1) << 4;
#pragma unroll
      for (int ni = 0; ni < 4; ++ni)
#pragma unroll
        for (int r = 0; r < 4; ++r)
          sc[(lhi * 4 + r) * 64 + ((ni * 16 + lane15) ^ swz)] = acc[ni][r];
      asm volatile("s_waitcnt lgkmcnt(0)" ::: "memory");
      __builtin_amdgcn_sched_barrier(0);
#pragma unroll
      for (int ii = 0; ii < 4; ++ii) {
        int flat4 = ii * 64 + lane;
        int lrow = flat4 >> 4;
        int c4 = flat4 & 15;
        int scol = (c4 * 4) ^ (((lrow >> 2) & 1) << 4);
        f32x4 a = *reinterpret_cast<const f32x4*>(&sc[lrow * 64 + scol]);
        int sres = (hbase >> 3) + (c4 >> 1);
        u16x4 pr = *reinterpret_cast<const u16x4*>(
            &p_lds[lrow * 1024 + ((sres ^ (lrow & 7)) << 3) + (c4 & 1) * 4]);
        float g = gs_l[lrow];
        f32x4 o;
        o[0] = bf2f(pr[0]) + g * a[0];
        o[1] = bf2f(pr[1]) + g * a[1];
        o[2] = bf2f(pr[2]) + g * a[2];
        o[3] = bf2f(pr[3]) + g * a[3];
        *reinterpret_cast<f32x4*>(&out[(gm0 + lrow) * H + hbase + c4 * 4]) = o;
      }
      asm volatile("s_waitcnt lgkmcnt(0)" ::: "memory");
    }
  }
}

extern "C" void kernel_launch(void* const* d_in, const int* in_sizes, int n_in,
                              void* d_out, int out_size, void* d_ws, size_t ws_size,
                              hipStream_t stream) {
  const float* p  = (const float*)d_in[0];
  const float* x  = (const float*)d_in[1];
  const float* Wq = (const float*)d_in[2];
  const float* bq = (const float*)d_in[3];
  const float* Wk = (const float*)d_in[4];
  const float* bk = (const float*)d_in[5];
  const float* Wv = (const float*)d_in[6];
  const float* bv = (const float*)d_in[7];
  const float* Wg = (const float*)d_in[8];
  const float* bg = (const float*)d_in[9];
  float* out = (float*)d_out;

  char* ws = (char*)d_ws;
  u16* wqTb    = (u16*)(ws);                    // 2 MiB
  u16* wkb     = (u16*)(ws + 2097152);          // 2 MiB
  u16* wvb     = (u16*)(ws + 4194304);          // 2 MiB
  u16* xb      = (u16*)(ws + 6291456);          // 1 MiB
  u16* kbf     = (u16*)(ws + 7340032);          // 1 MiB
  u16* ktb     = (u16*)(ws + 8388608);          // 1 MiB
  u16* vTb     = (u16*)(ws + 9437184);          // 1 MiB
  float* wgs   = (float*)(ws + 10485760);
  float* zeros = (float*)(ws + 10489856);
  float* vg    = (float*)(ws + 10493952);
  float* bqk   = (float*)(ws + 10498048);

  prep_kernel<<<897, 256, 0, stream>>>(Wq, Wk, Wv, x, Wg, wqTb, wkb, wvb, xb, wgs, zeros);
  kv1_kernel<<<64, 256, 0, stream>>>(xb, wkb, wvb, bk, bv, kbf, vTb);
  kv2_kernel<<<40, 256, 0, stream>>>(kbf, wqTb, zeros, ktb, vTb, Wg, bq, vg, bqk);
  attn_kernel<<<2048, 256, 0, stream>>>(p, ktb, vTb, wgs, vg, bqk, bg, out);
}

// Round 6
// 141.905 us; speedup vs baseline: 1.1367x; 1.1367x over previous
//
#include <hip/hip_runtime.h>

#define H 1024
#define SEQ 4096

typedef float f32x4 __attribute__((ext_vector_type(4)));
typedef short s16x8 __attribute__((ext_vector_type(8)));
typedef unsigned short u16;
typedef u16 u16x4 __attribute__((ext_vector_type(4)));
typedef u16 u16x8 __attribute__((ext_vector_type(8)));

__device__ inline u16 f2bf(float f) {
  union { float f; unsigned u; } v; v.f = f;
  unsigned r = v.u + 0x7fffu + ((v.u >> 16) & 1u);
  return (u16)(r >> 16);
}
__device__ inline float bf2f(u16 b) {
  union { unsigned u; float f; } v; v.u = ((unsigned)b) << 16; return v.f;
}

__device__ __forceinline__ void cvt16(const float* __restrict__ src, u16* __restrict__ dst, int i) {
  const float4* s = reinterpret_cast<const float4*>(src) + (size_t)i * 4;
  float4 a = s[0], b = s[1], c = s[2], d = s[3];
  u16x8 lo, hi;
  lo[0]=f2bf(a.x); lo[1]=f2bf(a.y); lo[2]=f2bf(a.z); lo[3]=f2bf(a.w);
  lo[4]=f2bf(b.x); lo[5]=f2bf(b.y); lo[6]=f2bf(b.z); lo[7]=f2bf(b.w);
  hi[0]=f2bf(c.x); hi[1]=f2bf(c.y); hi[2]=f2bf(c.z); hi[3]=f2bf(c.w);
  hi[4]=f2bf(d.x); hi[5]=f2bf(d.y); hi[6]=f2bf(d.z); hi[7]=f2bf(d.w);
  u16x8* o = reinterpret_cast<u16x8*>(dst) + (size_t)i * 2;
  o[0] = lo; o[1] = hi;
}

// =============== prep: Wq transpose, Wk/Wv/x cvt, wgs/zeros ===============
__global__ __launch_bounds__(256) void prep_kernel(
    const float* __restrict__ Wq, const float* __restrict__ Wk,
    const float* __restrict__ Wv, const float* __restrict__ x,
    const float* __restrict__ Wg,
    u16* __restrict__ wqTb, u16* __restrict__ wkb, u16* __restrict__ wvb,
    u16* __restrict__ xb, float* __restrict__ wgs, float* __restrict__ zeros) {
  __shared__ u16 tls[64][65];
  int blk = blockIdx.x, t = threadIdx.x;
  if (blk < 256) {
    int ti = blk >> 4, tj = blk & 15;
    int lr = t >> 2, cq = (t & 3) * 16;
    const float* s = Wq + (size_t)(ti * 64 + lr) * H + tj * 64 + cq;
#pragma unroll
    for (int q = 0; q < 4; ++q) {
      float4 v = *reinterpret_cast<const float4*>(s + q * 4);
      tls[lr][cq + q * 4 + 0] = f2bf(v.x);
      tls[lr][cq + q * 4 + 1] = f2bf(v.y);
      tls[lr][cq + q * 4 + 2] = f2bf(v.z);
      tls[lr][cq + q * 4 + 3] = f2bf(v.w);
    }
    __syncthreads();
    u16x8 a, b2;
#pragma unroll
    for (int i = 0; i < 8; ++i) a[i] = tls[cq + i][lr];
#pragma unroll
    for (int i = 0; i < 8; ++i) b2[i] = tls[cq + 8 + i][lr];
    u16* d = wqTb + (size_t)(tj * 64 + lr) * H + ti * 64 + cq;
    *reinterpret_cast<u16x8*>(d) = a;
    *reinterpret_cast<u16x8*>(d + 8) = b2;
  } else if (blk < 512) {
    cvt16(Wk, wkb, (blk - 256) * 256 + t);
  } else if (blk < 768) {
    cvt16(Wv, wvb, (blk - 512) * 256 + t);
  } else if (blk < 896) {
    cvt16(x, xb, (blk - 768) * 256 + t);
  } else {
    int i = t * 4;
    float4 a = *reinterpret_cast<const float4*>(Wg + i);
    float4 b2 = *reinterpret_cast<const float4*>(Wg + H + i);
    float4 o; o.x=a.x+b2.x; o.y=a.y+b2.y; o.z=a.z+b2.z; o.w=a.w+b2.w;
    *reinterpret_cast<float4*>(wgs + i) = o;
    float4 z; z.x=0.f; z.y=0.f; z.z=0.f; z.w=0.f;
    *reinterpret_cast<float4*>(zeros + i) = z;
  }
}

// ---- shared GEMM body: out = A(bf16 MxK) * W^T(bf16 NxK) + bias ----
__device__ __forceinline__ void gemm_body(const u16* __restrict__ A, const u16* __restrict__ W,
                                          const float* __restrict__ bias, u16* __restrict__ out,
                                          int mt, int nt, int omode, u16* sm) {
  int m0 = mt * 128, n0 = nt * 128;
  int t = threadIdx.x;
  int wave = t >> 6, lane = t & 63;
  int lane15 = lane & 15, lhi = lane >> 4;
  int wr = wave >> 1, wc = wave & 1;
  u16* a_sm = sm;
  u16* b_sm = sm + 8192;

  f32x4 acc[4][4];
#pragma unroll
  for (int mi = 0; mi < 4; ++mi)
#pragma unroll
    for (int ni = 0; ni < 4; ++ni) acc[mi][ni] = (f32x4)0.f;

  int rsel = wave * 32 + (lane >> 3);
  int csel = (lane & 7) * 8;
  const u16* Ab = A + (size_t)m0 * H + csel;
  const u16* Wb = W + (size_t)n0 * H + csel;

  for (int kt = 0; kt < 16; ++kt) {
    int kc = kt * 64;
#pragma unroll
    for (int j = 0; j < 4; ++j) {
      const u16* ga = Ab + (size_t)(rsel + j * 8) * H + kc;
      const u16* gb = Wb + (size_t)(rsel + j * 8) * H + kc;
      __builtin_amdgcn_global_load_lds((const __attribute__((address_space(1))) unsigned int*)ga,
                                       (__attribute__((address_space(3))) unsigned int*)&a_sm[wave * 2048 + j * 512],
                                       16, 0, 0);
      __builtin_amdgcn_global_load_lds((const __attribute__((address_space(1))) unsigned int*)gb,
                                       (__attribute__((address_space(3))) unsigned int*)&b_sm[wave * 2048 + j * 512],
                                       16, 0, 0);
    }
    __syncthreads();
#pragma unroll
    for (int ks = 0; ks < 2; ++ks) {
      s16x8 af[4], bfr[4];
#pragma unroll
      for (int mi = 0; mi < 4; ++mi)
        af[mi] = *reinterpret_cast<const s16x8*>(&a_sm[(wr * 64 + mi * 16 + lane15) * 64 + ks * 32 + lhi * 8]);
#pragma unroll
      for (int ni = 0; ni < 4; ++ni)
        bfr[ni] = *reinterpret_cast<const s16x8*>(&b_sm[(wc * 64 + ni * 16 + lane15) * 64 + ks * 32 + lhi * 8]);
#pragma unroll
      for (int mi = 0; mi < 4; ++mi)
#pragma unroll
        for (int ni = 0; ni < 4; ++ni)
          acc[mi][ni] = __builtin_amdgcn_mfma_f32_16x16x32_bf16(af[mi], bfr[ni], acc[mi][ni], 0, 0, 0);
    }
    __syncthreads();
  }

  float bqv[4];
#pragma unroll
  for (int ni = 0; ni < 4; ++ni) bqv[ni] = bias[n0 + wc * 64 + ni * 16 + lane15];

  if (omode == 0) {
#pragma unroll
    for (int mi = 0; mi < 4; ++mi)
#pragma unroll
      for (int ni = 0; ni < 4; ++ni)
#pragma unroll
        for (int r = 0; r < 4; ++r)
          sm[(wr * 64 + mi * 16 + lhi * 4 + r) * 128 + wc * 64 + ni * 16 + lane15] =
              f2bf(acc[mi][ni][r] + bqv[ni]);
    __syncthreads();
#pragma unroll
    for (int i = 0; i < 4; ++i) {
      int lin2 = i * 4096 + t * 16;
      int row = lin2 >> 7, col = lin2 & 127;
      u16x8 v0 = *reinterpret_cast<const u16x8*>(&sm[lin2]);
      u16x8 v1 = *reinterpret_cast<const u16x8*>(&sm[lin2 + 8]);
      u16* o = out + (size_t)(m0 + row) * H + n0 + col;
      *reinterpret_cast<u16x8*>(o) = v0;
      *reinterpret_cast<u16x8*>(o + 8) = v1;
    }
  } else {
#pragma unroll
    for (int mi = 0; mi < 4; ++mi)
#pragma unroll
      for (int ni = 0; ni < 4; ++ni) {
        int col = n0 + wc * 64 + ni * 16 + lane15;
#pragma unroll
        for (int r = 0; r < 4; ++r) {
          int row = m0 + wr * 64 + mi * 16 + lhi * 4 + r;
          out[((size_t)(row >> 6) * H + col) * 64 + (row & 63)] = f2bf(acc[mi][ni][r] + bqv[ni]);
        }
      }
  }
}

// kv1: k = x.Wk^T + bk (row-major), vT = (x.Wv^T + bv)^T
__global__ __launch_bounds__(256) void kv1_kernel(const u16* __restrict__ xb,
                                                  const u16* __restrict__ wkb, const u16* __restrict__ wvb,
                                                  const float* __restrict__ bk, const float* __restrict__ bv,
                                                  u16* __restrict__ kbf, u16* __restrict__ vTb) {
  __shared__ __align__(16) u16 sm[128 * 128];
  int sel = blockIdx.x >> 5;
  int bid = blockIdx.x & 31;
  if (sel == 0)
    gemm_body(xb, wkb, bk, kbf, bid >> 3, bid & 7, 0, sm);
  else
    gemm_body(xb, wvb, bv, vTb, bid >> 3, bid & 7, 2, sm);
}

// kv2: blocks 0-31: ktilde = k.Wq; blocks 32-39: vg = vT.Wg0, bqk = k.bq
__global__ __launch_bounds__(256) void kv2_kernel(const u16* __restrict__ kbf,
                                                  const u16* __restrict__ wqTb,
                                                  const float* __restrict__ zeros,
                                                  u16* __restrict__ ktb,
                                                  const u16* __restrict__ vTb,
                                                  const float* __restrict__ Wg,
                                                  const float* __restrict__ bq,
                                                  float* __restrict__ vg, float* __restrict__ bqk) {
  if (blockIdx.x < 32) {
    __shared__ __align__(16) u16 sm[128 * 128];
    gemm_body(kbf, wqTb, zeros, ktb, blockIdx.x >> 3, blockIdx.x & 7, 0, sm);
  } else {
    __shared__ float bq_s[H];
    __shared__ float partial[4][64];
    int b = blockIdx.x - 32, t = threadIdx.x;
    *reinterpret_cast<float4*>(&bq_s[t * 4]) = *reinterpret_cast<const float4*>(bq + t * 4);
    int l = t & 63, part = t >> 6;
    float s = 0.f;
    const u16* vtp = vTb + ((size_t)b * H + part * 256) * 64 + l;
    for (int h = 0; h < 256; ++h) s += bf2f(vtp[h * 64]) * Wg[part * 256 + h];
    partial[part][l] = s;
    __syncthreads();
    if (t < 64) vg[b * 64 + t] = partial[0][t] + partial[1][t] + partial[2][t] + partial[3][t];
    int row = t >> 2, qp = t & 3;
    const u16* kr = kbf + ((size_t)b * 64 + row) * H + qp * 256;
    float sb = 0.f;
    for (int j = 0; j < 256; j += 8) {
      u16x8 v8 = *reinterpret_cast<const u16x8*>(kr + j);
      const float* bqp = &bq_s[qp * 256 + j];
#pragma unroll
      for (int i2 = 0; i2 < 8; ++i2) sb += bf2f(v8[i2]) * bqp[i2];
    }
    sb += __shfl_xor(sb, 1);
    sb += __shfl_xor(sb, 2);
    if (qp == 0) bqk[b * 64 + row] = sb;
  }
}

// =============== fused attention: 16-row tiles, p staged once, COL-SPLIT S phase, 4 blocks/CU ===============
// Stage: p-tile 16x1024 f32 -> bf16 LDS (contiguous HBM reads). Barrier.
// S phase: wave w owns S cols [w*16,+16), full K: 32 iters x {1 LDS a-read, 1 L2 K~ read, 1 MFMA}.
//          No partials, no cross-wave deps. S -> S_lds (stride 68 f32). Barrier.
// Softmax: 16 thr/row; gate dot reads slots q+k8*16 (bank-spread); exp (no max-sub);
//          P-> P_lds bf16; gs = sigmoid(logit)/(32*sum). Barrier.
// PV: wave owns H-slice [w*256,+256); scratch ALIASES p_lds (dead); residual p re-read from
//     global (L3-absorbed, f32 precision). LDS ~39.4 KB -> 4 blocks/CU; grid 2048 = 2 generations.
__global__ __launch_bounds__(256, 4) void attn_kernel(
    const float* __restrict__ p, const u16* __restrict__ ktb,
    const u16* __restrict__ vT, const float* __restrict__ wgs,
    const float* __restrict__ vg, const float* __restrict__ bqk,
    const float* __restrict__ bg, float* __restrict__ out) {
  int t = threadIdx.x;
  int orig = blockIdx.x;
  int lin = (orig & 7) * 256 + (orig >> 3);  // batch-per-XCD locality (2048 = 8*256)
  int b = lin >> 8, st = lin & 255;
  size_t gm0 = (size_t)b * SEQ + (size_t)st * 16;
  int wave = t >> 6, lane = t & 63, lane15 = lane & 15, lhi = lane >> 4;

  __shared__ __align__(16) u16 p_lds[16 * 1024];   // 32 KB; 16B slot s of row r at s^(r&7); PV scratch aliases
  __shared__ __align__(16) float S_lds[16 * 68];   // 4.35 KB
  __shared__ __align__(16) u16 P_lds[16 * 72];     // 2.25 KB
  __shared__ float vg_l[64], bq_l[64], gs_l[16];

  if (t < 64) { vg_l[t] = vg[b * 64 + t]; bq_l[t] = bqk[b * 64 + t]; }

  // ---- stage p-tile (16 x 1024 f32 -> bf16 LDS), contiguous reads ----
  {
    int srow = t >> 7;            // 0..1
    int scol = t & 127;           // 16B slot within row
    const float* gp = p + (gm0 + srow) * H + scol * 8;
    f32x4 r0[8], r1[8];
#pragma unroll
    for (int i = 0; i < 8; ++i) {
      r0[i] = *reinterpret_cast<const f32x4*>(gp + (size_t)(2 * i) * H);
      r1[i] = *reinterpret_cast<const f32x4*>(gp + (size_t)(2 * i) * H + 4);
    }
#pragma unroll
    for (int i = 0; i < 8; ++i) {
      int row = 2 * i + srow;
      u16x8 o;
      o[0]=f2bf(r0[i][0]); o[1]=f2bf(r0[i][1]); o[2]=f2bf(r0[i][2]); o[3]=f2bf(r0[i][3]);
      o[4]=f2bf(r1[i][0]); o[5]=f2bf(r1[i][1]); o[6]=f2bf(r1[i][2]); o[7]=f2bf(r1[i][3]);
      *reinterpret_cast<u16x8*>(&p_lds[row * 1024 + ((scol ^ (row & 7)) << 3)]) = o;
    }
  }
  __syncthreads();

  // ---- S phase: col-split, full K per wave ----
  {
    const u16* kb = ktb + ((size_t)b * 64 + wave * 16 + lane15) * H + lhi * 8;
    f32x4 acc = (f32x4)0.f;
    int arow = lane15 * 1024;
    int aswz = lane15 & 7;
#pragma unroll 4
    for (int kt = 0; kt < 32; ++kt) {
      int kc = kt * 32;
      int sb = (kc >> 3) + lhi;
      s16x8 a = *reinterpret_cast<const s16x8*>(&p_lds[arow + ((sb ^ aswz) << 3)]);
      s16x8 k = *reinterpret_cast<const s16x8*>(kb + kc);
      acc = __builtin_amdgcn_mfma_f32_16x16x32_bf16(a, k, acc, 0, 0, 0);
    }
#pragma unroll
    for (int r = 0; r < 4; ++r)
      S_lds[(lhi * 4 + r) * 68 + wave * 16 + lane15] = acc[r];
  }
  __syncthreads();

  // ---- softmax + gate: 16 threads per row ----
  {
    int row = t >> 4, q = t & 15;
    int cq = q * 4;
    f32x4 s4 = *reinterpret_cast<const f32x4*>(&S_lds[row * 68 + cq]);
    float ev[4], se = 0.f, sv = 0.f;
#pragma unroll
    for (int j = 0; j < 4; ++j) {
      float e = __expf(s4[j] + bq_l[cq + j]);
      ev[j] = e; se += e; sv += e * vg_l[cq + j];
    }
    // gate dot pg: thread q reads slots q + k8*16 (bank-spread), h = slot*8
    float pg = 0.f;
    int prow = row * 1024, pswz = row & 7;
#pragma unroll
    for (int k8 = 0; k8 < 8; ++k8) {
      int s = q + k8 * 16;
      u16x8 pv8 = *reinterpret_cast<const u16x8*>(&p_lds[prow + ((s ^ pswz) << 3)]);
      const float* w_ = wgs + s * 8;
      pg += bf2f(pv8[0]) * w_[0] + bf2f(pv8[1]) * w_[1] + bf2f(pv8[2]) * w_[2] + bf2f(pv8[3]) * w_[3]
          + bf2f(pv8[4]) * w_[4] + bf2f(pv8[5]) * w_[5] + bf2f(pv8[6]) * w_[6] + bf2f(pv8[7]) * w_[7];
    }
    se += __shfl_xor(se, 1); se += __shfl_xor(se, 2); se += __shfl_xor(se, 4); se += __shfl_xor(se, 8);
    sv += __shfl_xor(sv, 1); sv += __shfl_xor(sv, 2); sv += __shfl_xor(sv, 4); sv += __shfl_xor(sv, 8);
    pg += __shfl_xor(pg, 1); pg += __shfl_xor(pg, 2); pg += __shfl_xor(pg, 4); pg += __shfl_xor(pg, 8);
    u16x4 pw;
#pragma unroll
    for (int j = 0; j < 4; ++j) pw[j] = f2bf(ev[j]);
    *reinterpret_cast<u16x4*>(&P_lds[row * 72 + cq]) = pw;
    if (q == 0) {
      float inv = 1.f / (32.f * se);
      float logit = sv * inv + pg + bg[0];
      gs_l[row] = inv / (1.f + __expf(-logit));
    }
  }
  __syncthreads();

  // ---- PV + epilogue: out = p + gs*(raw PV); wave owns H-slice [wave*256,+256) ----
  // scratch aliases p_lds (dead after softmax); residual p from global (L3)
  {
    s16x8 pa[2];
#pragma unroll
    for (int ks = 0; ks < 2; ++ks)
      pa[ks] = *reinterpret_cast<const s16x8*>(&P_lds[lane15 * 72 + ks * 32 + lhi * 8]);

    const u16* vb = vT + (size_t)b * H * 64;
    float* sc = reinterpret_cast<float*>(&p_lds[0]) + wave * 1024;  // [16][64] per wave
#pragma unroll
    for (int hcc = 0; hcc < 4; ++hcc) {
      int hbase = wave * 256 + hcc * 64;
      f32x4 acc[4];
#pragma unroll
      for (int ni = 0; ni < 4; ++ni) acc[ni] = (f32x4)0.f;
#pragma unroll
      for (int ks = 0; ks < 2; ++ks) {
        s16x8 bv8[4];
#pragma unroll
        for (int ni = 0; ni < 4; ++ni)
          bv8[ni] = *reinterpret_cast<const s16x8*>(vb + (size_t)(hbase + ni * 16 + lane15) * 64 + ks * 32 + lhi * 8);
#pragma unroll
        for (int ni = 0; ni < 4; ++ni)
          acc[ni] = __builtin_amdgcn_mfma_f32_16x16x32_bf16(pa[ks], bv8[ni], acc[ni], 0, 0, 0);
      }
      int swz = (lhi & 1) << 4;
#pragma unroll
      for (int ni = 0; ni < 4; ++ni)
#pragma unroll
        for (int r = 0; r < 4; ++r)
          sc[(lhi * 4 + r) * 64 + ((ni * 16 + lane15) ^ swz)] = acc[ni][r];
      asm volatile("s_waitcnt lgkmcnt(0)" ::: "memory");
      __builtin_amdgcn_sched_barrier(0);
#pragma unroll
      for (int ii = 0; ii < 4; ++ii) {
        int flat4 = ii * 64 + lane;
        int lrow = flat4 >> 4;
        int c4 = flat4 & 15;
        int scol = (c4 * 4) ^ (((lrow >> 2) & 1) << 4);
        f32x4 a = *reinterpret_cast<const f32x4*>(&sc[lrow * 64 + scol]);
        size_t grow = gm0 + lrow;
        float g = gs_l[lrow];
        float4 pr4 = *reinterpret_cast<const float4*>(&p[grow * H + hbase + c4 * 4]);
        f32x4 o;
        o[0] = pr4.x + g * a[0];
        o[1] = pr4.y + g * a[1];
        o[2] = pr4.z + g * a[2];
        o[3] = pr4.w + g * a[3];
        *reinterpret_cast<f32x4*>(&out[grow * H + hbase + c4 * 4]) = o;
      }
      asm volatile("s_waitcnt lgkmcnt(0)" ::: "memory");
    }
  }
}

extern "C" void kernel_launch(void* const* d_in, const int* in_sizes, int n_in,
                              void* d_out, int out_size, void* d_ws, size_t ws_size,
                              hipStream_t stream) {
  const float* p  = (const float*)d_in[0];
  const float* x  = (const float*)d_in[1];
  const float* Wq = (const float*)d_in[2];
  const float* bq = (const float*)d_in[3];
  const float* Wk = (const float*)d_in[4];
  const float* bk = (const float*)d_in[5];
  const float* Wv = (const float*)d_in[6];
  const float* bv = (const float*)d_in[7];
  const float* Wg = (const float*)d_in[8];
  const float* bg = (const float*)d_in[9];
  float* out = (float*)d_out;

  char* ws = (char*)d_ws;
  u16* wqTb    = (u16*)(ws);                    // 2 MiB
  u16* wkb     = (u16*)(ws + 2097152);          // 2 MiB
  u16* wvb     = (u16*)(ws + 4194304);          // 2 MiB
  u16* xb      = (u16*)(ws + 6291456);          // 1 MiB
  u16* kbf     = (u16*)(ws + 7340032);          // 1 MiB
  u16* ktb     = (u16*)(ws + 8388608);          // 1 MiB
  u16* vTb     = (u16*)(ws + 9437184);          // 1 MiB
  float* wgs   = (float*)(ws + 10485760);
  float* zeros = (float*)(ws + 10489856);
  float* vg    = (float*)(ws + 10493952);
  float* bqk   = (float*)(ws + 10498048);

  prep_kernel<<<897, 256, 0, stream>>>(Wq, Wk, Wv, x, Wg, wqTb, wkb, wvb, xb, wgs, zeros);
  kv1_kernel<<<64, 256, 0, stream>>>(xb, wkb, wvb, bk, bv, kbf, vTb);
  kv2_kernel<<<40, 256, 0, stream>>>(kbf, wqTb, zeros, ktb, vTb, Wg, bq, vg, bqk);
  attn_kernel<<<2048, 256, 0, stream>>>(p, ktb, vTb, wgs, vg, bqk, bg, out);
}

// Round 7
// 136.661 us; speedup vs baseline: 1.1803x; 1.0384x over previous
//
#include <hip/hip_runtime.h>

#define H 1024
#define SEQ 4096

typedef float f32x4 __attribute__((ext_vector_type(4)));
typedef short s16x8 __attribute__((ext_vector_type(8)));
typedef unsigned short u16;
typedef u16 u16x4 __attribute__((ext_vector_type(4)));
typedef u16 u16x8 __attribute__((ext_vector_type(8)));

__device__ inline u16 f2bf(float f) {
  union { float f; unsigned u; } v; v.f = f;
  unsigned r = v.u + 0x7fffu + ((v.u >> 16) & 1u);
  return (u16)(r >> 16);
}
__device__ inline float bf2f(u16 b) {
  union { unsigned u; float f; } v; v.u = ((unsigned)b) << 16; return v.f;
}

__device__ __forceinline__ void cvt16(const float* __restrict__ src, u16* __restrict__ dst, int i) {
  const float4* s = reinterpret_cast<const float4*>(src) + (size_t)i * 4;
  float4 a = s[0], b = s[1], c = s[2], d = s[3];
  u16x8 lo, hi;
  lo[0]=f2bf(a.x); lo[1]=f2bf(a.y); lo[2]=f2bf(a.z); lo[3]=f2bf(a.w);
  lo[4]=f2bf(b.x); lo[5]=f2bf(b.y); lo[6]=f2bf(b.z); lo[7]=f2bf(b.w);
  hi[0]=f2bf(c.x); hi[1]=f2bf(c.y); hi[2]=f2bf(c.z); hi[3]=f2bf(c.w);
  hi[4]=f2bf(d.x); hi[5]=f2bf(d.y); hi[6]=f2bf(d.z); hi[7]=f2bf(d.w);
  u16x8* o = reinterpret_cast<u16x8*>(dst) + (size_t)i * 2;
  o[0] = lo; o[1] = hi;
}

// =============== prep: Wq transpose, Wk/Wv/x cvt, wgs/zeros ===============
__global__ __launch_bounds__(256) void prep_kernel(
    const float* __restrict__ Wq, const float* __restrict__ Wk,
    const float* __restrict__ Wv, const float* __restrict__ x,
    const float* __restrict__ Wg,
    u16* __restrict__ wqTb, u16* __restrict__ wkb, u16* __restrict__ wvb,
    u16* __restrict__ xb, float* __restrict__ wgs, float* __restrict__ zeros) {
  __shared__ u16 tls[64][65];
  int blk = blockIdx.x, t = threadIdx.x;
  if (blk < 256) {
    int ti = blk >> 4, tj = blk & 15;
    int lr = t >> 2, cq = (t & 3) * 16;
    const float* s = Wq + (size_t)(ti * 64 + lr) * H + tj * 64 + cq;
#pragma unroll
    for (int q = 0; q < 4; ++q) {
      float4 v = *reinterpret_cast<const float4*>(s + q * 4);
      tls[lr][cq + q * 4 + 0] = f2bf(v.x);
      tls[lr][cq + q * 4 + 1] = f2bf(v.y);
      tls[lr][cq + q * 4 + 2] = f2bf(v.z);
      tls[lr][cq + q * 4 + 3] = f2bf(v.w);
    }
    __syncthreads();
    u16x8 a, b2;
#pragma unroll
    for (int i = 0; i < 8; ++i) a[i] = tls[cq + i][lr];
#pragma unroll
    for (int i = 0; i < 8; ++i) b2[i] = tls[cq + 8 + i][lr];
    u16* d = wqTb + (size_t)(tj * 64 + lr) * H + ti * 64 + cq;
    *reinterpret_cast<u16x8*>(d) = a;
    *reinterpret_cast<u16x8*>(d + 8) = b2;
  } else if (blk < 512) {
    cvt16(Wk, wkb, (blk - 256) * 256 + t);
  } else if (blk < 768) {
    cvt16(Wv, wvb, (blk - 512) * 256 + t);
  } else if (blk < 896) {
    cvt16(x, xb, (blk - 768) * 256 + t);
  } else {
    int i = t * 4;
    float4 a = *reinterpret_cast<const float4*>(Wg + i);
    float4 b2 = *reinterpret_cast<const float4*>(Wg + H + i);
    float4 o; o.x=a.x+b2.x; o.y=a.y+b2.y; o.z=a.z+b2.z; o.w=a.w+b2.w;
    *reinterpret_cast<float4*>(wgs + i) = o;
    float4 z; z.x=0.f; z.y=0.f; z.z=0.f; z.w=0.f;
    *reinterpret_cast<float4*>(zeros + i) = z;
  }
}

// ---- shared GEMM body: out = A(bf16 MxK) * W^T(bf16 NxK) + bias ----
__device__ __forceinline__ void gemm_body(const u16* __restrict__ A, const u16* __restrict__ W,
                                          const float* __restrict__ bias, u16* __restrict__ out,
                                          int mt, int nt, int omode, u16* sm) {
  int m0 = mt * 128, n0 = nt * 128;
  int t = threadIdx.x;
  int wave = t >> 6, lane = t & 63;
  int lane15 = lane & 15, lhi = lane >> 4;
  int wr = wave >> 1, wc = wave & 1;
  u16* a_sm = sm;
  u16* b_sm = sm + 8192;

  f32x4 acc[4][4];
#pragma unroll
  for (int mi = 0; mi < 4; ++mi)
#pragma unroll
    for (int ni = 0; ni < 4; ++ni) acc[mi][ni] = (f32x4)0.f;

  int rsel = wave * 32 + (lane >> 3);
  int csel = (lane & 7) * 8;
  const u16* Ab = A + (size_t)m0 * H + csel;
  const u16* Wb = W + (size_t)n0 * H + csel;

  for (int kt = 0; kt < 16; ++kt) {
    int kc = kt * 64;
#pragma unroll
    for (int j = 0; j < 4; ++j) {
      const u16* ga = Ab + (size_t)(rsel + j * 8) * H + kc;
      const u16* gb = Wb + (size_t)(rsel + j * 8) * H + kc;
      __builtin_amdgcn_global_load_lds((const __attribute__((address_space(1))) unsigned int*)ga,
                                       (__attribute__((address_space(3))) unsigned int*)&a_sm[wave * 2048 + j * 512],
                                       16, 0, 0);
      __builtin_amdgcn_global_load_lds((const __attribute__((address_space(1))) unsigned int*)gb,
                                       (__attribute__((address_space(3))) unsigned int*)&b_sm[wave * 2048 + j * 512],
                                       16, 0, 0);
    }
    __syncthreads();
#pragma unroll
    for (int ks = 0; ks < 2; ++ks) {
      s16x8 af[4], bfr[4];
#pragma unroll
      for (int mi = 0; mi < 4; ++mi)
        af[mi] = *reinterpret_cast<const s16x8*>(&a_sm[(wr * 64 + mi * 16 + lane15) * 64 + ks * 32 + lhi * 8]);
#pragma unroll
      for (int ni = 0; ni < 4; ++ni)
        bfr[ni] = *reinterpret_cast<const s16x8*>(&b_sm[(wc * 64 + ni * 16 + lane15) * 64 + ks * 32 + lhi * 8]);
#pragma unroll
      for (int mi = 0; mi < 4; ++mi)
#pragma unroll
        for (int ni = 0; ni < 4; ++ni)
          acc[mi][ni] = __builtin_amdgcn_mfma_f32_16x16x32_bf16(af[mi], bfr[ni], acc[mi][ni], 0, 0, 0);
    }
    __syncthreads();
  }

  float bqv[4];
#pragma unroll
  for (int ni = 0; ni < 4; ++ni) bqv[ni] = bias[n0 + wc * 64 + ni * 16 + lane15];

  if (omode == 0) {
#pragma unroll
    for (int mi = 0; mi < 4; ++mi)
#pragma unroll
      for (int ni = 0; ni < 4; ++ni)
#pragma unroll
        for (int r = 0; r < 4; ++r)
          sm[(wr * 64 + mi * 16 + lhi * 4 + r) * 128 + wc * 64 + ni * 16 + lane15] =
              f2bf(acc[mi][ni][r] + bqv[ni]);
    __syncthreads();
#pragma unroll
    for (int i = 0; i < 4; ++i) {
      int lin2 = i * 4096 + t * 16;
      int row = lin2 >> 7, col = lin2 & 127;
      u16x8 v0 = *reinterpret_cast<const u16x8*>(&sm[lin2]);
      u16x8 v1 = *reinterpret_cast<const u16x8*>(&sm[lin2 + 8]);
      u16* o = out + (size_t)(m0 + row) * H + n0 + col;
      *reinterpret_cast<u16x8*>(o) = v0;
      *reinterpret_cast<u16x8*>(o + 8) = v1;
    }
  } else {
#pragma unroll
    for (int mi = 0; mi < 4; ++mi)
#pragma unroll
      for (int ni = 0; ni < 4; ++ni) {
        int col = n0 + wc * 64 + ni * 16 + lane15;
#pragma unroll
        for (int r = 0; r < 4; ++r) {
          int row = m0 + wr * 64 + mi * 16 + lhi * 4 + r;
          out[((size_t)(row >> 6) * H + col) * 64 + (row & 63)] = f2bf(acc[mi][ni][r] + bqv[ni]);
        }
      }
  }
}

// kv1: k = x.Wk^T + bk (row-major), vT = (x.Wv^T + bv)^T
__global__ __launch_bounds__(256) void kv1_kernel(const u16* __restrict__ xb,
                                                  const u16* __restrict__ wkb, const u16* __restrict__ wvb,
                                                  const float* __restrict__ bk, const float* __restrict__ bv,
                                                  u16* __restrict__ kbf, u16* __restrict__ vTb) {
  __shared__ __align__(16) u16 sm[128 * 128];
  int sel = blockIdx.x >> 5;
  int bid = blockIdx.x & 31;
  if (sel == 0)
    gemm_body(xb, wkb, bk, kbf, bid >> 3, bid & 7, 0, sm);
  else
    gemm_body(xb, wvb, bv, vTb, bid >> 3, bid & 7, 2, sm);
}

// kv2: blocks 0-31: ktilde = k.Wq; blocks 32-39: vg = vT.Wg0, bqk = k.bq
__global__ __launch_bounds__(256) void kv2_kernel(const u16* __restrict__ kbf,
                                                  const u16* __restrict__ wqTb,
                                                  const float* __restrict__ zeros,
                                                  u16* __restrict__ ktb,
                                                  const u16* __restrict__ vTb,
                                                  const float* __restrict__ Wg,
                                                  const float* __restrict__ bq,
                                                  float* __restrict__ vg, float* __restrict__ bqk) {
  if (blockIdx.x < 32) {
    __shared__ __align__(16) u16 sm[128 * 128];
    gemm_body(kbf, wqTb, zeros, ktb, blockIdx.x >> 3, blockIdx.x & 7, 0, sm);
  } else {
    __shared__ float bq_s[H];
    __shared__ float partial[4][64];
    int b = blockIdx.x - 32, t = threadIdx.x;
    *reinterpret_cast<float4*>(&bq_s[t * 4]) = *reinterpret_cast<const float4*>(bq + t * 4);
    int l = t & 63, part = t >> 6;
    float s = 0.f;
    const u16* vtp = vTb + ((size_t)b * H + part * 256) * 64 + l;
    for (int h = 0; h < 256; ++h) s += bf2f(vtp[h * 64]) * Wg[part * 256 + h];
    partial[part][l] = s;
    __syncthreads();
    if (t < 64) vg[b * 64 + t] = partial[0][t] + partial[1][t] + partial[2][t] + partial[3][t];
    int row = t >> 2, qp = t & 3;
    const u16* kr = kbf + ((size_t)b * 64 + row) * H + qp * 256;
    float sb = 0.f;
    for (int j = 0; j < 256; j += 8) {
      u16x8 v8 = *reinterpret_cast<const u16x8*>(kr + j);
      const float* bqp = &bq_s[qp * 256 + j];
#pragma unroll
      for (int i2 = 0; i2 < 8; ++i2) sb += bf2f(v8[i2]) * bqp[i2];
    }
    sb += __shfl_xor(sb, 1);
    sb += __shfl_xor(sb, 2);
    if (qp == 0) bqk[b * 64 + row] = sb;
  }
}

// =============== attn kernel A: S + softmax -> P(bf16), gs (R4 phases 1-2, verified) ===============
// K-split: wave w owns k in [w*256,+256), direct scattered p reads (R4-proven pattern).
// Softmax 8 thr/row, no max-sub; P (raw e, bf16) + gs = sigmoid(logit)/(32*sum) to workspace.
__global__ __launch_bounds__(256, 4) void s_kernel(
    const float* __restrict__ p, const u16* __restrict__ ktb,
    const float* __restrict__ wgs, const float* __restrict__ vg,
    const float* __restrict__ bqk, const float* __restrict__ bg,
    u16* __restrict__ Pbuf, float* __restrict__ gsbuf) {
  int t = threadIdx.x;
  int orig = blockIdx.x;
  int lin = (orig & 7) * 128 + (orig >> 3);  // batch-per-XCD locality (1024 = 8*128)
  int b = lin >> 7, st = lin & 127;
  size_t gm0 = (size_t)b * SEQ + (size_t)st * 32;
  int wave = t >> 6, lane = t & 63, lane15 = lane & 15, lhi = lane >> 4;

  __shared__ __align__(16) float Sp[4][2048];   // 32 KB S-partials
  __shared__ float vg_l[64], bq_l[64], pg_part[4][32];

  if (t < 64) { vg_l[t] = vg[b * 64 + t]; bq_l[t] = bqk[b * 64 + t]; }

  // ---- phase 1: S-partial over wave's k-range (direct p reads) ----
  {
    const float* pb = p + (gm0 + lane15) * H;
    const u16* kb = ktb + ((size_t)b * 64 + lane15) * H;
    int kq = wave * 256 + lhi * 8;

    f32x4 acc[2][4];
#pragma unroll
    for (int mi = 0; mi < 2; ++mi)
#pragma unroll
      for (int ni = 0; ni < 4; ++ni) acc[mi][ni] = (f32x4)0.f;
    float pg0 = 0.f, pg1 = 0.f;

#pragma unroll 1
    for (int kt = 0; kt < 8; ++kt) {
      int kc = kq + kt * 32;
      f32x4 p0a = *reinterpret_cast<const f32x4*>(pb + kc);
      f32x4 p0b = *reinterpret_cast<const f32x4*>(pb + kc + 4);
      f32x4 p1a = *reinterpret_cast<const f32x4*>(pb + 16 * H + kc);
      f32x4 p1b = *reinterpret_cast<const f32x4*>(pb + 16 * H + kc + 4);
      s16x8 kf0 = *reinterpret_cast<const s16x8*>(kb + kc);
      s16x8 kf1 = *reinterpret_cast<const s16x8*>(kb + 16 * H + kc);
      s16x8 kf2 = *reinterpret_cast<const s16x8*>(kb + 32 * H + kc);
      s16x8 kf3 = *reinterpret_cast<const s16x8*>(kb + 48 * H + kc);
      f32x4 w0 = *reinterpret_cast<const f32x4*>(wgs + kc);
      f32x4 w1 = *reinterpret_cast<const f32x4*>(wgs + kc + 4);

      s16x8 a0, a1;
      a0[0]=f2bf(p0a[0]); a0[1]=f2bf(p0a[1]); a0[2]=f2bf(p0a[2]); a0[3]=f2bf(p0a[3]);
      a0[4]=f2bf(p0b[0]); a0[5]=f2bf(p0b[1]); a0[6]=f2bf(p0b[2]); a0[7]=f2bf(p0b[3]);
      a1[0]=f2bf(p1a[0]); a1[1]=f2bf(p1a[1]); a1[2]=f2bf(p1a[2]); a1[3]=f2bf(p1a[3]);
      a1[4]=f2bf(p1b[0]); a1[5]=f2bf(p1b[1]); a1[6]=f2bf(p1b[2]); a1[7]=f2bf(p1b[3]);

      acc[0][0] = __builtin_amdgcn_mfma_f32_16x16x32_bf16(a0, kf0, acc[0][0], 0, 0, 0);
      acc[0][1] = __builtin_amdgcn_mfma_f32_16x16x32_bf16(a0, kf1, acc[0][1], 0, 0, 0);
      acc[0][2] = __builtin_amdgcn_mfma_f32_16x16x32_bf16(a0, kf2, acc[0][2], 0, 0, 0);
      acc[0][3] = __builtin_amdgcn_mfma_f32_16x16x32_bf16(a0, kf3, acc[0][3], 0, 0, 0);
      acc[1][0] = __builtin_amdgcn_mfma_f32_16x16x32_bf16(a1, kf0, acc[1][0], 0, 0, 0);
      acc[1][1] = __builtin_amdgcn_mfma_f32_16x16x32_bf16(a1, kf1, acc[1][1], 0, 0, 0);
      acc[1][2] = __builtin_amdgcn_mfma_f32_16x16x32_bf16(a1, kf2, acc[1][2], 0, 0, 0);
      acc[1][3] = __builtin_amdgcn_mfma_f32_16x16x32_bf16(a1, kf3, acc[1][3], 0, 0, 0);

      pg0 += p0a[0]*w0[0] + p0a[1]*w0[1] + p0a[2]*w0[2] + p0a[3]*w0[3]
           + p0b[0]*w1[0] + p0b[1]*w1[1] + p0b[2]*w1[2] + p0b[3]*w1[3];
      pg1 += p1a[0]*w0[0] + p1a[1]*w0[1] + p1a[2]*w0[2] + p1a[3]*w0[3]
           + p1b[0]*w1[0] + p1b[1]*w1[1] + p1b[2]*w1[2] + p1b[3]*w1[3];
    }

    pg0 += __shfl_xor(pg0, 16); pg0 += __shfl_xor(pg0, 32);
    pg1 += __shfl_xor(pg1, 16); pg1 += __shfl_xor(pg1, 32);
    if (lane < 16) { pg_part[wave][lane15] = pg0; pg_part[wave][16 + lane15] = pg1; }

    float* sp = &Sp[wave][0];
#pragma unroll
    for (int mi = 0; mi < 2; ++mi)
#pragma unroll
      for (int ni = 0; ni < 4; ++ni)
#pragma unroll
        for (int r = 0; r < 4; ++r)
          sp[(mi * 16 + lhi * 4 + r) * 64 + ni * 16 + lane15] = acc[mi][ni][r];
  }
  __syncthreads();

  // ---- softmax: 8 threads per row; write P (raw e) + gs to workspace ----
  {
    int row = t >> 3, c0 = (t & 7) * 8;
    f32x4 sA = (f32x4)0.f, sB = (f32x4)0.f;
#pragma unroll
    for (int w = 0; w < 4; ++w) {
      sA += *reinterpret_cast<const f32x4*>(&Sp[w][row * 64 + c0]);
      sB += *reinterpret_cast<const f32x4*>(&Sp[w][row * 64 + c0 + 4]);
    }
    float ev[8];
    float se = 0.f, sv = 0.f;
#pragma unroll
    for (int j = 0; j < 4; ++j) {
      float e = __expf(sA[j] + bq_l[c0 + j]);
      ev[j] = e; se += e; sv += e * vg_l[c0 + j];
    }
#pragma unroll
    for (int j = 0; j < 4; ++j) {
      float e = __expf(sB[j] + bq_l[c0 + 4 + j]);
      ev[4 + j] = e; se += e; sv += e * vg_l[c0 + 4 + j];
    }
    se += __shfl_xor(se, 1); se += __shfl_xor(se, 2); se += __shfl_xor(se, 4);
    sv += __shfl_xor(sv, 1); sv += __shfl_xor(sv, 2); sv += __shfl_xor(sv, 4);
    u16x8 pw;
#pragma unroll
    for (int j = 0; j < 8; ++j) pw[j] = f2bf(ev[j]);
    *reinterpret_cast<u16x8*>(&Pbuf[(size_t)lin * 2048 + row * 64 + c0]) = pw;
    if ((t & 7) == 0) {
      float pg = pg_part[0][row] + pg_part[1][row] + pg_part[2][row] + pg_part[3][row];
      float inv = 1.f / (32.f * se);
      float logit = sv * inv + pg + bg[0];
      gsbuf[lin * 32 + row] = inv / (1.f + __expf(-logit));
    }
  }
}

// =============== attn kernel B: PV + epilogue (R4 phase 3, verified) ===============
// pa frags direct from Pbuf (global, MFMA layout); V from L2; residual p from L3; out to HBM.
__global__ __launch_bounds__(256, 4) void pv_kernel(
    const float* __restrict__ p, const u16* __restrict__ vT,
    const u16* __restrict__ Pbuf, const float* __restrict__ gsbuf,
    float* __restrict__ out) {
  int t = threadIdx.x;
  int orig = blockIdx.x;
  int lin = (orig & 7) * 128 + (orig >> 3);  // same mapping as s_kernel
  int b = lin >> 7, st = lin & 127;
  size_t gm0 = (size_t)b * SEQ + (size_t)st * 32;
  int wave = t >> 6, lane = t & 63, lane15 = lane & 15, lhi = lane >> 4;

  __shared__ __align__(16) float sc_all[4][2048];  // 32 KB transpose scratch
  __shared__ float gs_l[32];

  if (t < 32) gs_l[t] = gsbuf[lin * 32 + t];

  s16x8 pa[2][2];
  const u16* pfb = Pbuf + (size_t)lin * 2048;
#pragma unroll
  for (int mi = 0; mi < 2; ++mi)
#pragma unroll
    for (int ks = 0; ks < 2; ++ks)
      pa[mi][ks] = *reinterpret_cast<const s16x8*>(pfb + (mi * 16 + lane15) * 64 + ks * 32 + lhi * 8);
  __syncthreads();

  const u16* vb = vT + (size_t)b * H * 64;
  float* sc = &sc_all[wave][0];
#pragma unroll
  for (int hcc = 0; hcc < 4; ++hcc) {
    int hbase = wave * 256 + hcc * 64;
    f32x4 acc[2][4];
#pragma unroll
    for (int mi = 0; mi < 2; ++mi)
#pragma unroll
      for (int ni = 0; ni < 4; ++ni) acc[mi][ni] = (f32x4)0.f;
#pragma unroll
    for (int ks = 0; ks < 2; ++ks) {
      s16x8 bv8[4];
#pragma unroll
      for (int ni = 0; ni < 4; ++ni)
        bv8[ni] = *reinterpret_cast<const s16x8*>(vb + (size_t)(hbase + ni * 16 + lane15) * 64 + ks * 32 + lhi * 8);
#pragma unroll
      for (int mi = 0; mi < 2; ++mi)
#pragma unroll
        for (int ni = 0; ni < 4; ++ni)
          acc[mi][ni] = __builtin_amdgcn_mfma_f32_16x16x32_bf16(pa[mi][ks], bv8[ni], acc[mi][ni], 0, 0, 0);
    }
    int swz = (lhi & 1) << 4;
#pragma unroll
    for (int mi = 0; mi < 2; ++mi)
#pragma unroll
      for (int ni = 0; ni < 4; ++ni)
#pragma unroll
        for (int r = 0; r < 4; ++r)
          sc[(mi * 16 + lhi * 4 + r) * 64 + ((ni * 16 + lane15) ^ swz)] = acc[mi][ni][r];
    asm volatile("s_waitcnt lgkmcnt(0)" ::: "memory");
    __builtin_amdgcn_sched_barrier(0);
#pragma unroll
    for (int ii = 0; ii < 8; ++ii) {
      int flat4 = ii * 64 + lane;
      int lrow = flat4 >> 4;
      int c4 = flat4 & 15;
      int scol = (c4 * 4) ^ (((lrow >> 2) & 1) << 4);
      f32x4 a = *reinterpret_cast<const f32x4*>(&sc[lrow * 64 + scol]);
      size_t grow = gm0 + lrow;
      float g = gs_l[lrow];
      float4 pr4 = *reinterpret_cast<const float4*>(&p[grow * H + hbase + c4 * 4]);
      f32x4 o;
      o[0] = pr4.x + g * a[0];
      o[1] = pr4.y + g * a[1];
      o[2] = pr4.z + g * a[2];
      o[3] = pr4.w + g * a[3];
      *reinterpret_cast<f32x4*>(&out[grow * H + hbase + c4 * 4]) = o;
    }
    asm volatile("s_waitcnt lgkmcnt(0)" ::: "memory");
  }
}

extern "C" void kernel_launch(void* const* d_in, const int* in_sizes, int n_in,
                              void* d_out, int out_size, void* d_ws, size_t ws_size,
                              hipStream_t stream) {
  const float* p  = (const float*)d_in[0];
  const float* x  = (const float*)d_in[1];
  const float* Wq = (const float*)d_in[2];
  const float* bq = (const float*)d_in[3];
  const float* Wk = (const float*)d_in[4];
  const float* bk = (const float*)d_in[5];
  const float* Wv = (const float*)d_in[6];
  const float* bv = (const float*)d_in[7];
  const float* Wg = (const float*)d_in[8];
  const float* bg = (const float*)d_in[9];
  float* out = (float*)d_out;

  char* ws = (char*)d_ws;
  u16* wqTb    = (u16*)(ws);                    // 2 MiB
  u16* wkb     = (u16*)(ws + 2097152);          // 2 MiB (dead after kv1 -> Pbuf aliases)
  u16* wvb     = (u16*)(ws + 4194304);          // 2 MiB (dead after kv1 -> Pbuf aliases)
  u16* xb      = (u16*)(ws + 6291456);          // 1 MiB (dead after kv1 -> gsbuf aliases)
  u16* kbf     = (u16*)(ws + 7340032);          // 1 MiB
  u16* ktb     = (u16*)(ws + 8388608);          // 1 MiB
  u16* vTb     = (u16*)(ws + 9437184);          // 1 MiB
  float* wgs   = (float*)(ws + 10485760);
  float* zeros = (float*)(ws + 10489856);
  float* vg    = (float*)(ws + 10493952);
  float* bqk   = (float*)(ws + 10498048);
  u16* Pbuf    = (u16*)(ws + 2097152);          // 4 MiB (aliases wkb+wvb, dead by then)
  float* gsbuf = (float*)(ws + 6291456);        // 128 KiB (aliases xb, dead by then)

  prep_kernel<<<897, 256, 0, stream>>>(Wq, Wk, Wv, x, Wg, wqTb, wkb, wvb, xb, wgs, zeros);
  kv1_kernel<<<64, 256, 0, stream>>>(xb, wkb, wvb, bk, bv, kbf, vTb);
  kv2_kernel<<<40, 256, 0, stream>>>(kbf, wqTb, zeros, ktb, vTb, Wg, bq, vg, bqk);
  s_kernel<<<1024, 256, 0, stream>>>(p, ktb, wgs, vg, bqk, bg, Pbuf, gsbuf);
  pv_kernel<<<1024, 256, 0, stream>>>(p, vTb, Pbuf, gsbuf, out);
}

// Round 8
// 128.341 us; speedup vs baseline: 1.2569x; 1.0648x over previous
//
#include <hip/hip_runtime.h>

#define H 1024
#define SEQ 4096

typedef float f32x4 __attribute__((ext_vector_type(4)));
typedef short s16x8 __attribute__((ext_vector_type(8)));
typedef unsigned short u16;
typedef u16 u16x4 __attribute__((ext_vector_type(4)));
typedef u16 u16x8 __attribute__((ext_vector_type(8)));

__device__ inline u16 f2bf(float f) {
  union { float f; unsigned u; } v; v.f = f;
  unsigned r = v.u + 0x7fffu + ((v.u >> 16) & 1u);
  return (u16)(r >> 16);
}
__device__ inline float bf2f(u16 b) {
  union { unsigned u; float f; } v; v.u = ((unsigned)b) << 16; return v.f;
}

__device__ __forceinline__ void cvt16(const float* __restrict__ src, u16* __restrict__ dst, int i) {
  const float4* s = reinterpret_cast<const float4*>(src) + (size_t)i * 4;
  float4 a = s[0], b = s[1], c = s[2], d = s[3];
  u16x8 lo, hi;
  lo[0]=f2bf(a.x); lo[1]=f2bf(a.y); lo[2]=f2bf(a.z); lo[3]=f2bf(a.w);
  lo[4]=f2bf(b.x); lo[5]=f2bf(b.y); lo[6]=f2bf(b.z); lo[7]=f2bf(b.w);
  hi[0]=f2bf(c.x); hi[1]=f2bf(c.y); hi[2]=f2bf(c.z); hi[3]=f2bf(c.w);
  hi[4]=f2bf(d.x); hi[5]=f2bf(d.y); hi[6]=f2bf(d.z); hi[7]=f2bf(d.w);
  u16x8* o = reinterpret_cast<u16x8*>(dst) + (size_t)i * 2;
  o[0] = lo; o[1] = hi;
}

// =============== prep: Wq transpose, Wk/Wv/x cvt, wgs/zeros ===============
__global__ __launch_bounds__(256) void prep_kernel(
    const float* __restrict__ Wq, const float* __restrict__ Wk,
    const float* __restrict__ Wv, const float* __restrict__ x,
    const float* __restrict__ Wg,
    u16* __restrict__ wqTb, u16* __restrict__ wkb, u16* __restrict__ wvb,
    u16* __restrict__ xb, float* __restrict__ wgs, float* __restrict__ zeros) {
  __shared__ u16 tls[64][65];
  int blk = blockIdx.x, t = threadIdx.x;
  if (blk < 256) {
    int ti = blk >> 4, tj = blk & 15;
    int lr = t >> 2, cq = (t & 3) * 16;
    const float* s = Wq + (size_t)(ti * 64 + lr) * H + tj * 64 + cq;
#pragma unroll
    for (int q = 0; q < 4; ++q) {
      float4 v = *reinterpret_cast<const float4*>(s + q * 4);
      tls[lr][cq + q * 4 + 0] = f2bf(v.x);
      tls[lr][cq + q * 4 + 1] = f2bf(v.y);
      tls[lr][cq + q * 4 + 2] = f2bf(v.z);
      tls[lr][cq + q * 4 + 3] = f2bf(v.w);
    }
    __syncthreads();
    u16x8 a, b2;
#pragma unroll
    for (int i = 0; i < 8; ++i) a[i] = tls[cq + i][lr];
#pragma unroll
    for (int i = 0; i < 8; ++i) b2[i] = tls[cq + 8 + i][lr];
    u16* d = wqTb + (size_t)(tj * 64 + lr) * H + ti * 64 + cq;
    *reinterpret_cast<u16x8*>(d) = a;
    *reinterpret_cast<u16x8*>(d + 8) = b2;
  } else if (blk < 512) {
    cvt16(Wk, wkb, (blk - 256) * 256 + t);
  } else if (blk < 768) {
    cvt16(Wv, wvb, (blk - 512) * 256 + t);
  } else if (blk < 896) {
    cvt16(x, xb, (blk - 768) * 256 + t);
  } else {
    int i = t * 4;
    float4 a = *reinterpret_cast<const float4*>(Wg + i);
    float4 b2 = *reinterpret_cast<const float4*>(Wg + H + i);
    float4 o; o.x=a.x+b2.x; o.y=a.y+b2.y; o.z=a.z+b2.z; o.w=a.w+b2.w;
    *reinterpret_cast<float4*>(wgs + i) = o;
    float4 z; z.x=0.f; z.y=0.f; z.z=0.f; z.w=0.f;
    *reinterpret_cast<float4*>(zeros + i) = z;
  }
}

// ---- shared GEMM body: out = A(bf16 MxK) * W^T(bf16 NxK) + bias ----
__device__ __forceinline__ void gemm_body(const u16* __restrict__ A, const u16* __restrict__ W,
                                          const float* __restrict__ bias, u16* __restrict__ out,
                                          int mt, int nt, int omode, u16* sm) {
  int m0 = mt * 128, n0 = nt * 128;
  int t = threadIdx.x;
  int wave = t >> 6, lane = t & 63;
  int lane15 = lane & 15, lhi = lane >> 4;
  int wr = wave >> 1, wc = wave & 1;
  u16* a_sm = sm;
  u16* b_sm = sm + 8192;

  f32x4 acc[4][4];
#pragma unroll
  for (int mi = 0; mi < 4; ++mi)
#pragma unroll
    for (int ni = 0; ni < 4; ++ni) acc[mi][ni] = (f32x4)0.f;

  int rsel = wave * 32 + (lane >> 3);
  int csel = (lane & 7) * 8;
  const u16* Ab = A + (size_t)m0 * H + csel;
  const u16* Wb = W + (size_t)n0 * H + csel;

  for (int kt = 0; kt < 16; ++kt) {
    int kc = kt * 64;
#pragma unroll
    for (int j = 0; j < 4; ++j) {
      const u16* ga = Ab + (size_t)(rsel + j * 8) * H + kc;
      const u16* gb = Wb + (size_t)(rsel + j * 8) * H + kc;
      __builtin_amdgcn_global_load_lds((const __attribute__((address_space(1))) unsigned int*)ga,
                                       (__attribute__((address_space(3))) unsigned int*)&a_sm[wave * 2048 + j * 512],
                                       16, 0, 0);
      __builtin_amdgcn_global_load_lds((const __attribute__((address_space(1))) unsigned int*)gb,
                                       (__attribute__((address_space(3))) unsigned int*)&b_sm[wave * 2048 + j * 512],
                                       16, 0, 0);
    }
    __syncthreads();
#pragma unroll
    for (int ks = 0; ks < 2; ++ks) {
      s16x8 af[4], bfr[4];
#pragma unroll
      for (int mi = 0; mi < 4; ++mi)
        af[mi] = *reinterpret_cast<const s16x8*>(&a_sm[(wr * 64 + mi * 16 + lane15) * 64 + ks * 32 + lhi * 8]);
#pragma unroll
      for (int ni = 0; ni < 4; ++ni)
        bfr[ni] = *reinterpret_cast<const s16x8*>(&b_sm[(wc * 64 + ni * 16 + lane15) * 64 + ks * 32 + lhi * 8]);
#pragma unroll
      for (int mi = 0; mi < 4; ++mi)
#pragma unroll
        for (int ni = 0; ni < 4; ++ni)
          acc[mi][ni] = __builtin_amdgcn_mfma_f32_16x16x32_bf16(af[mi], bfr[ni], acc[mi][ni], 0, 0, 0);
    }
    __syncthreads();
  }

  float bqv[4];
#pragma unroll
  for (int ni = 0; ni < 4; ++ni) bqv[ni] = bias[n0 + wc * 64 + ni * 16 + lane15];

  if (omode == 0) {
#pragma unroll
    for (int mi = 0; mi < 4; ++mi)
#pragma unroll
      for (int ni = 0; ni < 4; ++ni)
#pragma unroll
        for (int r = 0; r < 4; ++r)
          sm[(wr * 64 + mi * 16 + lhi * 4 + r) * 128 + wc * 64 + ni * 16 + lane15] =
              f2bf(acc[mi][ni][r] + bqv[ni]);
    __syncthreads();
#pragma unroll
    for (int i = 0; i < 4; ++i) {
      int lin2 = i * 4096 + t * 16;
      int row = lin2 >> 7, col = lin2 & 127;
      u16x8 v0 = *reinterpret_cast<const u16x8*>(&sm[lin2]);
      u16x8 v1 = *reinterpret_cast<const u16x8*>(&sm[lin2 + 8]);
      u16* o = out + (size_t)(m0 + row) * H + n0 + col;
      *reinterpret_cast<u16x8*>(o) = v0;
      *reinterpret_cast<u16x8*>(o + 8) = v1;
    }
  } else {
#pragma unroll
    for (int mi = 0; mi < 4; ++mi)
#pragma unroll
      for (int ni = 0; ni < 4; ++ni) {
        int col = n0 + wc * 64 + ni * 16 + lane15;
#pragma unroll
        for (int r = 0; r < 4; ++r) {
          int row = m0 + wr * 64 + mi * 16 + lhi * 4 + r;
          out[((size_t)(row >> 6) * H + col) * 64 + (row & 63)] = f2bf(acc[mi][ni][r] + bqv[ni]);
        }
      }
  }
}

// kv1: k = x.Wk^T + bk (row-major), vT = (x.Wv^T + bv)^T
__global__ __launch_bounds__(256) void kv1_kernel(const u16* __restrict__ xb,
                                                  const u16* __restrict__ wkb, const u16* __restrict__ wvb,
                                                  const float* __restrict__ bk, const float* __restrict__ bv,
                                                  u16* __restrict__ kbf, u16* __restrict__ vTb) {
  __shared__ __align__(16) u16 sm[128 * 128];
  int sel = blockIdx.x >> 5;
  int bid = blockIdx.x & 31;
  if (sel == 0)
    gemm_body(xb, wkb, bk, kbf, bid >> 3, bid & 7, 0, sm);
  else
    gemm_body(xb, wvb, bv, vTb, bid >> 3, bid & 7, 2, sm);
}

// kv2: blocks 0-31: ktilde = k.Wq; blocks 32-39: vg = vT.Wg0, bqk = k.bq
__global__ __launch_bounds__(256) void kv2_kernel(const u16* __restrict__ kbf,
                                                  const u16* __restrict__ wqTb,
                                                  const float* __restrict__ zeros,
                                                  u16* __restrict__ ktb,
                                                  const u16* __restrict__ vTb,
                                                  const float* __restrict__ Wg,
                                                  const float* __restrict__ bq,
                                                  float* __restrict__ vg, float* __restrict__ bqk) {
  if (blockIdx.x < 32) {
    __shared__ __align__(16) u16 sm[128 * 128];
    gemm_body(kbf, wqTb, zeros, ktb, blockIdx.x >> 3, blockIdx.x & 7, 0, sm);
  } else {
    __shared__ float bq_s[H];
    __shared__ float partial[4][64];
    int b = blockIdx.x - 32, t = threadIdx.x;
    *reinterpret_cast<float4*>(&bq_s[t * 4]) = *reinterpret_cast<const float4*>(bq + t * 4);
    int l = t & 63, part = t >> 6;
    float s = 0.f;
    const u16* vtp = vTb + ((size_t)b * H + part * 256) * 64 + l;
    for (int h = 0; h < 256; ++h) s += bf2f(vtp[h * 64]) * Wg[part * 256 + h];
    partial[part][l] = s;
    __syncthreads();
    if (t < 64) vg[b * 64 + t] = partial[0][t] + partial[1][t] + partial[2][t] + partial[3][t];
    int row = t >> 2, qp = t & 3;
    const u16* kr = kbf + ((size_t)b * 64 + row) * H + qp * 256;
    float sb = 0.f;
    for (int j = 0; j < 256; j += 8) {
      u16x8 v8 = *reinterpret_cast<const u16x8*>(kr + j);
      const float* bqp = &bq_s[qp * 256 + j];
#pragma unroll
      for (int i2 = 0; i2 < 8; ++i2) sb += bf2f(v8[i2]) * bqp[i2];
    }
    sb += __shfl_xor(sb, 1);
    sb += __shfl_xor(sb, 2);
    if (qp == 0) bqk[b * 64 + row] = sb;
  }
}

// =============== fused attention: K-split waves + LEAN p-register double-buffer ===============
// R4 structure (verified 103us) with ONE change: phase-1 ping-pongs p-fragments (pA/pB) so each
// wave keeps 4KB of HBM reads in flight across a full consume-half (counted waits via reg deps).
// K~ frags loaded per-half (L2-hot, hidden under the p-only cvt chain). Everything else identical.
__global__ __launch_bounds__(256, 4) void attn_kernel(
    const float* __restrict__ p, const u16* __restrict__ ktb,
    const u16* __restrict__ vT, const float* __restrict__ wgs,
    const float* __restrict__ vg, const float* __restrict__ bqk,
    const float* __restrict__ bg, float* __restrict__ out) {
  int t = threadIdx.x;
  int orig = blockIdx.x;
  int lin = (orig & 7) * 128 + (orig >> 3);  // batch-per-XCD locality (1024 = 8*128)
  int b = lin >> 7, st = lin & 127;
  size_t gm0 = (size_t)b * SEQ + (size_t)st * 32;
  int wave = t >> 6, lane = t & 63, lane15 = lane & 15, lhi = lane >> 4;

  __shared__ __align__(16) float Sp[4][2048];   // 32 KB: S-partials; epilogue scratch aliases
  __shared__ __align__(16) u16 P_lds[32 * 72];  // 4.6 KB
  __shared__ float vg_l[64], bq_l[64], pg_part[4][32], gs_l[32];

  if (t < 64) { vg_l[t] = vg[b * 64 + t]; bq_l[t] = bqk[b * 64 + t]; }

  // ---- phase 1: S-partial over wave's k-range, p double-buffered in registers ----
  {
    const float* pb = p + (gm0 + lane15) * H;
    const u16* kb = ktb + ((size_t)b * 64 + lane15) * H;
    int kq = wave * 256 + lhi * 8;

    f32x4 acc[2][4];
#pragma unroll
    for (int mi = 0; mi < 2; ++mi)
#pragma unroll
      for (int ni = 0; ni < 4; ++ni) acc[mi][ni] = (f32x4)0.f;
    float pg0 = 0.f, pg1 = 0.f;

    f32x4 pA[4], pB[4];
    s16x8 kf[4];

#define LDP(P, kc)                                                        \
    {                                                                     \
      P[0] = *reinterpret_cast<const f32x4*>(pb + (kc));                  \
      P[1] = *reinterpret_cast<const f32x4*>(pb + (kc) + 4);              \
      P[2] = *reinterpret_cast<const f32x4*>(pb + 16 * H + (kc));         \
      P[3] = *reinterpret_cast<const f32x4*>(pb + 16 * H + (kc) + 4);     \
    }
#define LDK(kc)                                                           \
    {                                                                     \
      kf[0] = *reinterpret_cast<const s16x8*>(kb + (kc));                 \
      kf[1] = *reinterpret_cast<const s16x8*>(kb + 16 * H + (kc));        \
      kf[2] = *reinterpret_cast<const s16x8*>(kb + 32 * H + (kc));        \
      kf[3] = *reinterpret_cast<const s16x8*>(kb + 48 * H + (kc));        \
    }
#define CONS(P, kc)                                                       \
    {                                                                     \
      f32x4 w0 = *reinterpret_cast<const f32x4*>(wgs + (kc));             \
      f32x4 w1 = *reinterpret_cast<const f32x4*>(wgs + (kc) + 4);         \
      s16x8 a0, a1;                                                       \
      a0[0]=f2bf(P[0][0]); a0[1]=f2bf(P[0][1]); a0[2]=f2bf(P[0][2]); a0[3]=f2bf(P[0][3]); \
      a0[4]=f2bf(P[1][0]); a0[5]=f2bf(P[1][1]); a0[6]=f2bf(P[1][2]); a0[7]=f2bf(P[1][3]); \
      a1[0]=f2bf(P[2][0]); a1[1]=f2bf(P[2][1]); a1[2]=f2bf(P[2][2]); a1[3]=f2bf(P[2][3]); \
      a1[4]=f2bf(P[3][0]); a1[5]=f2bf(P[3][1]); a1[6]=f2bf(P[3][2]); a1[7]=f2bf(P[3][3]); \
      acc[0][0] = __builtin_amdgcn_mfma_f32_16x16x32_bf16(a0, kf[0], acc[0][0], 0, 0, 0); \
      acc[0][1] = __builtin_amdgcn_mfma_f32_16x16x32_bf16(a0, kf[1], acc[0][1], 0, 0, 0); \
      acc[0][2] = __builtin_amdgcn_mfma_f32_16x16x32_bf16(a0, kf[2], acc[0][2], 0, 0, 0); \
      acc[0][3] = __builtin_amdgcn_mfma_f32_16x16x32_bf16(a0, kf[3], acc[0][3], 0, 0, 0); \
      acc[1][0] = __builtin_amdgcn_mfma_f32_16x16x32_bf16(a1, kf[0], acc[1][0], 0, 0, 0); \
      acc[1][1] = __builtin_amdgcn_mfma_f32_16x16x32_bf16(a1, kf[1], acc[1][1], 0, 0, 0); \
      acc[1][2] = __builtin_amdgcn_mfma_f32_16x16x32_bf16(a1, kf[2], acc[1][2], 0, 0, 0); \
      acc[1][3] = __builtin_amdgcn_mfma_f32_16x16x32_bf16(a1, kf[3], acc[1][3], 0, 0, 0); \
      pg0 += P[0][0]*w0[0] + P[0][1]*w0[1] + P[0][2]*w0[2] + P[0][3]*w0[3]  \
           + P[1][0]*w1[0] + P[1][1]*w1[1] + P[1][2]*w1[2] + P[1][3]*w1[3]; \
      pg1 += P[2][0]*w0[0] + P[2][1]*w0[1] + P[2][2]*w0[2] + P[2][3]*w0[3]  \
           + P[3][0]*w1[0] + P[3][1]*w1[1] + P[3][2]*w1[2] + P[3][3]*w1[3]; \
    }

    LDP(pA, kq);
#pragma unroll 1
    for (int kt2 = 0; kt2 < 4; ++kt2) {
      int kc0 = kq + kt2 * 64;
      LDP(pB, kc0 + 32);      // prefetch half 2 while half 1 is consumed
      LDK(kc0);
      CONS(pA, kc0);
      if (kt2 < 3) LDP(pA, kc0 + 64);  // prefetch next iter's half 1
      LDK(kc0 + 32);
      CONS(pB, kc0 + 32);
    }
#undef LDP
#undef LDK
#undef CONS

    pg0 += __shfl_xor(pg0, 16); pg0 += __shfl_xor(pg0, 32);
    pg1 += __shfl_xor(pg1, 16); pg1 += __shfl_xor(pg1, 32);
    if (lane < 16) { pg_part[wave][lane15] = pg0; pg_part[wave][16 + lane15] = pg1; }

    float* sp = &Sp[wave][0];
#pragma unroll
    for (int mi = 0; mi < 2; ++mi)
#pragma unroll
      for (int ni = 0; ni < 4; ++ni)
#pragma unroll
        for (int r = 0; r < 4; ++r)
          sp[(mi * 16 + lhi * 4 + r) * 64 + ni * 16 + lane15] = acc[mi][ni][r];
  }
  __syncthreads();

  // ---- softmax: 8 threads per row ----
  {
    int row = t >> 3, c0 = (t & 7) * 8;
    f32x4 sA = (f32x4)0.f, sB = (f32x4)0.f;
#pragma unroll
    for (int w = 0; w < 4; ++w) {
      sA += *reinterpret_cast<const f32x4*>(&Sp[w][row * 64 + c0]);
      sB += *reinterpret_cast<const f32x4*>(&Sp[w][row * 64 + c0 + 4]);
    }
    float ev[8];
    float se = 0.f, sv = 0.f;
#pragma unroll
    for (int j = 0; j < 4; ++j) {
      float e = __expf(sA[j] + bq_l[c0 + j]);
      ev[j] = e; se += e; sv += e * vg_l[c0 + j];
    }
#pragma unroll
    for (int j = 0; j < 4; ++j) {
      float e = __expf(sB[j] + bq_l[c0 + 4 + j]);
      ev[4 + j] = e; se += e; sv += e * vg_l[c0 + 4 + j];
    }
    se += __shfl_xor(se, 1); se += __shfl_xor(se, 2); se += __shfl_xor(se, 4);
    sv += __shfl_xor(sv, 1); sv += __shfl_xor(sv, 2); sv += __shfl_xor(sv, 4);
    u16x8 pw;
#pragma unroll
    for (int j = 0; j < 8; ++j) pw[j] = f2bf(ev[j]);
    *reinterpret_cast<u16x8*>(&P_lds[row * 72 + c0]) = pw;
    if ((t & 7) == 0) {
      float pg = pg_part[0][row] + pg_part[1][row] + pg_part[2][row] + pg_part[3][row];
      float inv = 1.f / (32.f * se);
      float logit = sv * inv + pg + bg[0];
      gs_l[row] = inv / (1.f + __expf(-logit));
    }
  }
  __syncthreads();

  // ---- PV + coalesced epilogue: out = p + gs*(raw PV) ; wave owns H-slice [wave*256,+256) ----
  {
    s16x8 pa[2][2];
#pragma unroll
    for (int mi = 0; mi < 2; ++mi)
#pragma unroll
      for (int ks = 0; ks < 2; ++ks)
        pa[mi][ks] = *reinterpret_cast<const s16x8*>(&P_lds[(mi * 16 + lane15) * 72 + ks * 32 + lhi * 8]);

    const u16* vb = vT + (size_t)b * H * 64;
    float* sc = &Sp[0][0] + wave * 2048;  // [32][64] per wave (aliases S-partials, consumed)
#pragma unroll
    for (int hcc = 0; hcc < 4; ++hcc) {
      int hbase = wave * 256 + hcc * 64;
      f32x4 acc[2][4];
#pragma unroll
      for (int mi = 0; mi < 2; ++mi)
#pragma unroll
        for (int ni = 0; ni < 4; ++ni) acc[mi][ni] = (f32x4)0.f;
#pragma unroll
      for (int ks = 0; ks < 2; ++ks) {
        s16x8 bv8[4];
#pragma unroll
        for (int ni = 0; ni < 4; ++ni)
          bv8[ni] = *reinterpret_cast<const s16x8*>(vb + (size_t)(hbase + ni * 16 + lane15) * 64 + ks * 32 + lhi * 8);
#pragma unroll
        for (int mi = 0; mi < 2; ++mi)
#pragma unroll
          for (int ni = 0; ni < 4; ++ni)
            acc[mi][ni] = __builtin_amdgcn_mfma_f32_16x16x32_bf16(pa[mi][ks], bv8[ni], acc[mi][ni], 0, 0, 0);
      }
      int swz = (lhi & 1) << 4;
#pragma unroll
      for (int mi = 0; mi < 2; ++mi)
#pragma unroll
        for (int ni = 0; ni < 4; ++ni)
#pragma unroll
          for (int r = 0; r < 4; ++r)
            sc[(mi * 16 + lhi * 4 + r) * 64 + ((ni * 16 + lane15) ^ swz)] = acc[mi][ni][r];
      asm volatile("s_waitcnt lgkmcnt(0)" ::: "memory");
      __builtin_amdgcn_sched_barrier(0);
#pragma unroll
      for (int ii = 0; ii < 8; ++ii) {
        int flat4 = ii * 64 + lane;
        int lrow = flat4 >> 4;
        int c4 = flat4 & 15;
        int scol = (c4 * 4) ^ (((lrow >> 2) & 1) << 4);
        f32x4 a = *reinterpret_cast<const f32x4*>(&sc[lrow * 64 + scol]);
        size_t grow = gm0 + lrow;
        float g = gs_l[lrow];
        float4 pr4 = *reinterpret_cast<const float4*>(&p[grow * H + hbase + c4 * 4]);
        f32x4 o;
        o[0] = pr4.x + g * a[0];
        o[1] = pr4.y + g * a[1];
        o[2] = pr4.z + g * a[2];
        o[3] = pr4.w + g * a[3];
        *reinterpret_cast<f32x4*>(&out[grow * H + hbase + c4 * 4]) = o;
      }
      asm volatile("s_waitcnt lgkmcnt(0)" ::: "memory");
    }
  }
}

extern "C" void kernel_launch(void* const* d_in, const int* in_sizes, int n_in,
                              void* d_out, int out_size, void* d_ws, size_t ws_size,
                              hipStream_t stream) {
  const float* p  = (const float*)d_in[0];
  const float* x  = (const float*)d_in[1];
  const float* Wq = (const float*)d_in[2];
  const float* bq = (const float*)d_in[3];
  const float* Wk = (const float*)d_in[4];
  const float* bk = (const float*)d_in[5];
  const float* Wv = (const float*)d_in[6];
  const float* bv = (const float*)d_in[7];
  const float* Wg = (const float*)d_in[8];
  const float* bg = (const float*)d_in[9];
  float* out = (float*)d_out;

  char* ws = (char*)d_ws;
  u16* wqTb    = (u16*)(ws);                    // 2 MiB
  u16* wkb     = (u16*)(ws + 2097152);          // 2 MiB
  u16* wvb     = (u16*)(ws + 4194304);          // 2 MiB
  u16* xb      = (u16*)(ws + 6291456);          // 1 MiB
  u16* kbf     = (u16*)(ws + 7340032);          // 1 MiB
  u16* ktb     = (u16*)(ws + 8388608);          // 1 MiB
  u16* vTb     = (u16*)(ws + 9437184);          // 1 MiB
  float* wgs   = (float*)(ws + 10485760);
  float* zeros = (float*)(ws + 10489856);
  float* vg    = (float*)(ws + 10493952);
  float* bqk   = (float*)(ws + 10498048);

  prep_kernel<<<897, 256, 0, stream>>>(Wq, Wk, Wv, x, Wg, wqTb, wkb, wvb, xb, wgs, zeros);
  kv1_kernel<<<64, 256, 0, stream>>>(xb, wkb, wvb, bk, bv, kbf, vTb);
  kv2_kernel<<<40, 256, 0, stream>>>(kbf, wqTb, zeros, ktb, vTb, Wg, bq, vg, bqk);
  attn_kernel<<<1024, 256, 0, stream>>>(p, ktb, vTb, wgs, vg, bqk, bg, out);
}